// Round 1
// 13292.915 us; speedup vs baseline: 1.1041x; 1.1041x over previous
//
#include <hip/hip_runtime.h>
#include <hip/hip_bf16.h>

#define UNITS 1024
#define FEAT  16
#define TSTEPS 512
#define OUTSTEPS 24
#define BATCH 256
#define KTOT  1088   // 16 (x) + 1024 (h) + 48 pad
#define KP    1096   // padded LDS stride: 2192B = 137 x 16B -> stride%8(16B units)==1, conflict-free b128
#define NROWS 4096   // 4*UNITS, reordered r = 4*u + gate

#define SMEM_BYTES (64 * KP * 2 + 2048)   // Ws slice + hstage = 142,336 B

typedef __bf16 bf16x8 __attribute__((ext_vector_type(8)));
typedef float  f32x4  __attribute__((ext_vector_type(4)));

__device__ __forceinline__ float sigmoidf_(float x) { return 1.f / (1.f + __expf(-x)); }
__device__ __forceinline__ float tanhf_(float x)    { return 1.f - 2.f / (__expf(2.f * x) + 1.f); }

// ---------------------------------------------------------------------------
// Build Wcat_T[r][k] (bf16, row-major, stride KTOT), r = 4*u + g -> orig col
// c = g*1024 + u.  k<16: kernel[k][c]; 16<=k<1040: rec_kernel[k-16][c]; else 0.
// ---------------------------------------------------------------------------
__global__ __launch_bounds__(256) void prep_weights(const float* __restrict__ kern,
                                                    const float* __restrict__ rec,
                                                    __bf16* __restrict__ Wcat) {
    __shared__ __align__(16) __bf16 tile[64][72];
    int r0 = blockIdx.x * 64;          // 64 r-tiles
    int k0 = blockIdx.y * 64;          // 17 k-tiles
    int t  = threadIdx.x;
    int c_off = t & 63;                // which of the 64 r's (as (g,ui))
    int k_grp = t >> 6;                // 0..3, 16 k's each
    int g = c_off >> 4, ui = c_off & 15;
    int u0 = r0 >> 2;
    int c  = g * 1024 + u0 + ui;       // original column in (F/U x 4096) weights
    int rl = 4 * ui + g;               // local r
    for (int i = 0; i < 16; i++) {
        int k = k0 + k_grp * 16 + i;
        float v = 0.f;
        if (k < 16)        v = kern[(size_t)k * NROWS + c];
        else if (k < 1040) v = rec[(size_t)(k - 16) * NROWS + c];
        tile[rl][k_grp * 16 + i] = (__bf16)v;
    }
    __syncthreads();
    int rl2 = t >> 2, ch = t & 3;      // write 16 cols per thread
    bf16x8* dst = (bf16x8*)(Wcat + (size_t)(r0 + rl2) * KTOT + k0 + ch * 16);
    const bf16x8* src = (const bf16x8*)&tile[rl2][ch * 16];
    dst[0] = src[0];
    dst[1] = src[1];
}

// ---------------------------------------------------------------------------
// Zero hT/cT (contiguous), zero+x-init Abuf buffers, zero barrier counters.
// ---------------------------------------------------------------------------
__global__ __launch_bounds__(256) void prep_state(const float* __restrict__ x,
                                                  __bf16* __restrict__ Ab0,
                                                  __bf16* __restrict__ Ab1,
                                                  float* __restrict__ hc,
                                                  unsigned int* __restrict__ ctr) {
    int tid = blockIdx.x * 256 + threadIdx.x;
    int np  = gridDim.x * 256;
    for (int i = tid; i < 2 * BATCH * UNITS; i += np) hc[i] = 0.f;
    const int AB = BATCH * KTOT;  // 278528
    for (int i = tid; i < 2 * AB; i += np) {
        int which = (i < AB) ? 0 : 1;
        int p = i - which * AB;
        int col = p % KTOT;
        int m   = p / KTOT;
        __bf16 v = (__bf16)0.f;
        if (which == 0 && col < FEAT) v = (__bf16)x[(size_t)m * TSTEPS * FEAT + col];
        if (which == 0) Ab0[p] = v; else Ab1[p] = v;
    }
    for (int i = tid; i < 512 * 4 * 16; i += np) ctr[i] = 0u;
}

// ---------------------------------------------------------------------------
// Precompute per-(t,m): tv = x[m][t][0], keep-flag = all 16 feats == -1.
// ---------------------------------------------------------------------------
__global__ __launch_bounds__(256) void prep_tv(const float* __restrict__ x,
                                               float* __restrict__ tvx,
                                               unsigned char* __restrict__ kflag) {
    int m = blockIdx.x;
    for (int t = threadIdx.x; t < TSTEPS; t += 256) {
        const float* row = x + ((size_t)m * TSTEPS + t) * FEAT;
        f32x4 v0 = *(const f32x4*)row;
        f32x4 v1 = *(const f32x4*)(row + 4);
        f32x4 v2 = *(const f32x4*)(row + 8);
        f32x4 v3 = *(const f32x4*)(row + 12);
        bool keep = true;
#pragma unroll
        for (int i = 0; i < 4; ++i)
            keep = keep && (v0[i] == -1.f) && (v1[i] == -1.f) &&
                   (v2[i] == -1.f) && (v3[i] == -1.f);
        tvx[(size_t)t * BATCH + m]   = v0[0];
        kflag[(size_t)t * BATCH + m] = keep ? 1 : 0;
    }
}

// ---------------------------------------------------------------------------
// Gate + phased update for one (unit, batch) pair held entirely in one lane.
// ---------------------------------------------------------------------------
__device__ __forceinline__ void gate_update(
    float z0, float z1, float z2, float z3,
    float bi, float bf, float bg, float bo,
    float ph, float rp, float ro, float k2,
    float tv, int kf, float& h, float& c) {
    float zi = z0 + bi, zf = z1 + bf, zg = z2 + bg, zo = z3 + bo;
    float ig = sigmoidf_(zi), fg = sigmoidf_(zf), og = sigmoidf_(zo);
    float gv = tanhf_(zg);
    float nc = fg * c + ig * gv;
    float nh = og * tanhf_(nc);
    float cr = (tv - ph) * rp;
    cr = cr - floorf(cr);                       // == mod(tv-ph, per)/per
    float kup = cr * k2;                        // 2*cr/ro
    float kk = (cr < ro) ? (2.f - kup) : (0.001f * cr);
    kk = (cr < 0.5f * ro) ? kup : kk;
    float ho = kk * nh + (1.f - kk) * h;
    float co = kk * nc + (1.f - kk) * c;
    if (kf) { ho = h; co = c; }
    h = ho; c = co;
}

// ---------------------------------------------------------------------------
// Persistent multi-step PLSTM kernel.
// Grid 256 x 256 thr, 1 block/CU (forced by 142KB LDS).
// Block (gb = batch-group 0..3, rb = weight-row-block 0..63):
//   - Wcat rows [rb*64, rb*64+64) resident in LDS for all steps (MFMA A-op).
//   - Activations Abuf rows [gb*64, gb*64+64) streamed from L2 (MFMA B-op).
//   - Swapped operands: D[row]=r=4u+g, D[col]=batch -> each lane's 4 acc regs
//     are i,f,g,o of ONE (u, m) pair. h/c live in registers across all steps.
//   - Per-step sync: agent-scope atomic counter over the 64 blocks of group gb.
// nsteps==1 (AR): no barrier, h/c round-trip through hT/cT (transposed [u][m]).
// ---------------------------------------------------------------------------
__global__ __launch_bounds__(256, 1) void rnn_steps(
    const __bf16* __restrict__ Wcat,
    __bf16* __restrict__ Ab0, __bf16* __restrict__ Ab1,
    float* __restrict__ hT, float* __restrict__ cT,
    const float* __restrict__ bias, const float* __restrict__ period,
    const float* __restrict__ phase, const float* __restrict__ ratio,
    const float* __restrict__ tvx, const unsigned char* __restrict__ kflag,
    const float* __restrict__ tsrc, int tv_mstride,
    const float* __restrict__ xg,
    unsigned int* ctr, int nsteps, int par0) {
    extern __shared__ __align__(16) char smem[];
    __bf16* Ws     = (__bf16*)smem;                   // [64][KP]
    __bf16* hstage = (__bf16*)(smem + 64 * KP * 2);   // [64 m][16 u]

    int b   = blockIdx.x;
    int gb  = (b & 7) >> 1;                 // batch group 0..3 (XCD pair shares group)
    int rb  = ((b >> 3) << 1) | (b & 1);    // weight row-block 0..63
    int tid = threadIdx.x;
    int lane = tid & 63, wave = tid >> 6;
    int wr = wave >> 1, wm = wave & 1;      // wave splits: r-half, m-half
    int l16 = lane & 15, quad = lane >> 4;
    int gm0 = gb * 64;
    int r0  = rb * 64;
    int u0  = rb * 16;

    // ---- one-time: stage Wcat slice into LDS (padded stride KP) ----
    for (int i = tid; i < 64 * 136; i += 256) {
        int rr = i / 136, cc = i - rr * 136;
        *(bf16x8*)&Ws[rr * KP + cc * 8] =
            *(const bf16x8*)&Wcat[(size_t)(r0 + rr) * KTOT + cc * 8];
    }

    // ---- static per-lane constants ----
    int mm0 = gm0 + wm * 32 + l16;          // batch index, bt=0
    int mm1 = mm0 + 16;                     // bt=1
    int uuA = u0 + wr * 8 + quad;           // unit, rt=0
    int uuB = uuA + 4;                      // rt=1
    float Bi0 = bias[uuA],             Bi1 = bias[uuB];
    float Bf0 = bias[UNITS + uuA],     Bf1 = bias[UNITS + uuB];
    float Bg0 = bias[2 * UNITS + uuA], Bg1 = bias[2 * UNITS + uuB];
    float Bo0 = bias[3 * UNITS + uuA], Bo1 = bias[3 * UNITS + uuB];
    float Ph0 = phase[uuA], Ph1 = phase[uuB];
    float Rp0 = 1.f / period[uuA], Rp1 = 1.f / period[uuB];
    float Ro0 = ratio[uuA], Ro1 = ratio[uuB];
    float K20 = 2.f / Ro0,  K21 = 2.f / Ro1;

    float h00 = hT[(size_t)uuA * BATCH + mm0], h01 = hT[(size_t)uuA * BATCH + mm1];
    float h10 = hT[(size_t)uuB * BATCH + mm0], h11 = hT[(size_t)uuB * BATCH + mm1];
    float c00 = cT[(size_t)uuA * BATCH + mm0], c01 = cT[(size_t)uuA * BATCH + mm1];
    float c10 = cT[(size_t)uuB * BATCH + mm0], c11 = cT[(size_t)uuB * BATCH + mm1];

    const __bf16* ws0 = Ws + (wr * 32 + l16) * KP + quad * 8;   // rt=0 A-frags
    const __bf16* ws1 = ws0 + 16 * KP;                          // rt=1

    bool warm = (tvx != nullptr);

    __syncthreads();   // Ws ready

    for (int t = 0; t < nsteps; ++t) {
        int par = (par0 + t) & 1;
        const __bf16* Ar = par ? Ab1 : Ab0;
        __bf16*       Aw = par ? Ab0 : Ab1;

        const __bf16* b0p = Ar + (size_t)mm0 * KTOT + quad * 8;
        const __bf16* b1p = Ar + (size_t)mm1 * KTOT + quad * 8;

        f32x4 acc[2][2] = {};
#pragma unroll
        for (int kt = 0; kt < 34; ++kt) {
            bf16x8 av0 = *(const bf16x8*)(ws0 + kt * 32);
            bf16x8 av1 = *(const bf16x8*)(ws1 + kt * 32);
            bf16x8 bv0 = *(const bf16x8*)(b0p + kt * 32);
            bf16x8 bv1 = *(const bf16x8*)(b1p + kt * 32);
            acc[0][0] = __builtin_amdgcn_mfma_f32_16x16x32_bf16(av0, bv0, acc[0][0], 0, 0, 0);
            acc[0][1] = __builtin_amdgcn_mfma_f32_16x16x32_bf16(av0, bv1, acc[0][1], 0, 0, 0);
            acc[1][0] = __builtin_amdgcn_mfma_f32_16x16x32_bf16(av1, bv0, acc[1][0], 0, 0, 0);
            acc[1][1] = __builtin_amdgcn_mfma_f32_16x16x32_bf16(av1, bv1, acc[1][1], 0, 0, 0);
        }

        float tvv0, tvv1;
        int kf0 = 0, kf1 = 0;
        if (warm) {
            tvv0 = tvx[(size_t)t * BATCH + mm0];
            tvv1 = tvx[(size_t)t * BATCH + mm1];
            kf0  = kflag[(size_t)t * BATCH + mm0];
            kf1  = kflag[(size_t)t * BATCH + mm1];
        } else {
            tvv0 = tsrc[(size_t)mm0 * tv_mstride];
            tvv1 = tsrc[(size_t)mm1 * tv_mstride];
        }

        gate_update(acc[0][0][0], acc[0][0][1], acc[0][0][2], acc[0][0][3],
                    Bi0, Bf0, Bg0, Bo0, Ph0, Rp0, Ro0, K20, tvv0, kf0, h00, c00);
        hstage[(wm * 32 + l16) * 16 + wr * 8 + quad] = (__bf16)h00;
        gate_update(acc[0][1][0], acc[0][1][1], acc[0][1][2], acc[0][1][3],
                    Bi0, Bf0, Bg0, Bo0, Ph0, Rp0, Ro0, K20, tvv1, kf1, h01, c01);
        hstage[(wm * 32 + 16 + l16) * 16 + wr * 8 + quad] = (__bf16)h01;
        gate_update(acc[1][0][0], acc[1][0][1], acc[1][0][2], acc[1][0][3],
                    Bi1, Bf1, Bg1, Bo1, Ph1, Rp1, Ro1, K21, tvv0, kf0, h10, c10);
        hstage[(wm * 32 + l16) * 16 + wr * 8 + 4 + quad] = (__bf16)h10;
        gate_update(acc[1][1][0], acc[1][1][1], acc[1][1][2], acc[1][1][3],
                    Bi1, Bf1, Bg1, Bo1, Ph1, Rp1, Ro1, K21, tvv1, kf1, h11, c11);
        hstage[(wm * 32 + 16 + l16) * 16 + wr * 8 + 4 + quad] = (__bf16)h11;

        __syncthreads();
        {   // coalesced copy-out: 16 contiguous units per batch row
            int ml = tid >> 2, c4 = tid & 3;
            uint2 v = *(const uint2*)&hstage[ml * 16 + c4 * 4];
            *(uint2*)&Aw[(size_t)(gm0 + ml) * KTOT + 16 + u0 + c4 * 4] = v;
        }
        // stage next-step x into cols 0..15 (warm phase, one block per group)
        if (xg != nullptr && rb == 0 && t + 1 < nsteps && tid < 128) {
            int row = tid >> 1, half = tid & 1;
            const float* src = xg + ((size_t)(gm0 + row) * TSTEPS + (t + 1)) * FEAT + half * 8;
            bf16x8 o;
#pragma unroll
            for (int i = 0; i < 8; ++i) o[i] = (__bf16)src[i];
            *(bf16x8*)&Aw[(size_t)(gm0 + row) * KTOT + half * 8] = o;
        }

        if (t + 1 < nsteps) {
            __syncthreads();   // all stores of this block issued+drained
            if (tid == 0) {
                unsigned int* cp_ = ctr + ((size_t)t * 4 + gb) * 16;
                __hip_atomic_fetch_add(cp_, 1u, __ATOMIC_RELEASE, __HIP_MEMORY_SCOPE_AGENT);
                while (__hip_atomic_load(cp_, __ATOMIC_RELAXED, __HIP_MEMORY_SCOPE_AGENT) < 64u)
                    __builtin_amdgcn_s_sleep(2);
                __builtin_amdgcn_fence(__ATOMIC_ACQUIRE, "agent");
            }
            __syncthreads();
        }
    }

    // dump register state (transposed layout [u][m])
    hT[(size_t)uuA * BATCH + mm0] = h00; hT[(size_t)uuA * BATCH + mm1] = h01;
    hT[(size_t)uuB * BATCH + mm0] = h10; hT[(size_t)uuB * BATCH + mm1] = h11;
    cT[(size_t)uuA * BATCH + mm0] = c00; cT[(size_t)uuA * BATCH + mm1] = c01;
    cT[(size_t)uuB * BATCH + mm0] = c10; cT[(size_t)uuB * BATCH + mm1] = c11;
}

// ---------------------------------------------------------------------------
// Dense layer 1: a1 = tanh(hT^T @ w1 + b1), hT is [UNITS][BATCH] transposed.
// ---------------------------------------------------------------------------
__global__ __launch_bounds__(256) void dense1T(const float* __restrict__ hT,
                                               const float* __restrict__ w1,
                                               const float* __restrict__ b1,
                                               float* __restrict__ a1) {
    int m0 = blockIdx.x * 4;
    int j = threadIdx.x;
    float s0 = 0.f, s1 = 0.f, s2 = 0.f, s3 = 0.f;
    for (int k = 0; k < UNITS; k++) {
        float w = w1[(size_t)k * 256 + j];
        const float* hrow = hT + (size_t)k * BATCH + m0;
        s0 += hrow[0] * w;
        s1 += hrow[1] * w;
        s2 += hrow[2] * w;
        s3 += hrow[3] * w;
    }
    float bb = b1[j];
    a1[(size_t)(m0 + 0) * 256 + j] = tanhf_(s0 + bb);
    a1[(size_t)(m0 + 1) * 256 + j] = tanhf_(s1 + bb);
    a1[(size_t)(m0 + 2) * 256 + j] = tanhf_(s2 + bb);
    a1[(size_t)(m0 + 3) * 256 + j] = tanhf_(s3 + bb);
}

// ---------------------------------------------------------------------------
// Dense tail: L2,L3,L4 fused. Grid 32 blocks x 256 thr; block does 8 rows.
// Writes pred into d_out[:, s, :] and (bf16) into Abuf_x cols 0..15.
// ---------------------------------------------------------------------------
__global__ __launch_bounds__(256) void dense_tail(
    const float* __restrict__ a1, const float* __restrict__ w2, const float* __restrict__ b2,
    const float* __restrict__ w3, const float* __restrict__ b3, const float* __restrict__ wo,
    const float* __restrict__ bo, float* __restrict__ out, __bf16* __restrict__ Abuf_x, int s) {
    __shared__ float a1s[8][256];
    __shared__ float a2s[8][128];
    __shared__ float a3s[8][64];
    int m0 = blockIdx.x * 8;
    int t = threadIdx.x;
    for (int i = 0; i < 8; i++) {
        int idx = t + i * 256;
        int r = idx >> 8, c = idx & 255;
        a1s[r][c] = a1[(size_t)(m0 + r) * 256 + c];
    }
    __syncthreads();
    {   // L2: 256 -> 128
        int j = t & 127, rb = t >> 7;
        float acc[4] = {0.f, 0.f, 0.f, 0.f};
        for (int k = 0; k < 256; k++) {
            float w = w2[(size_t)k * 128 + j];
#pragma unroll
            for (int q = 0; q < 4; q++) acc[q] += a1s[rb * 4 + q][k] * w;
        }
        float bb = b2[j];
#pragma unroll
        for (int q = 0; q < 4; q++) a2s[rb * 4 + q][j] = tanhf_(acc[q] + bb);
    }
    __syncthreads();
    {   // L3: 128 -> 64
        int j = t & 63, rb = t >> 6;
        float acc[2] = {0.f, 0.f};
        for (int k = 0; k < 128; k++) {
            float w = w3[(size_t)k * 64 + j];
#pragma unroll
            for (int q = 0; q < 2; q++) acc[q] += a2s[rb * 2 + q][k] * w;
        }
        float bb = b3[j];
#pragma unroll
        for (int q = 0; q < 2; q++) a3s[rb * 2 + q][j] = tanhf_(acc[q] + bb);
    }
    __syncthreads();
    if (t < 128) {  // L4: 64 -> 16
        int j = t & 15, r = t >> 4;
        float acc = 0.f;
        for (int k = 0; k < 64; k++) acc += a3s[r][k] * wo[(size_t)k * 16 + j];
        float v = acc + bo[j];
        out[(size_t)(m0 + r) * (OUTSTEPS * FEAT) + s * FEAT + j] = v;
        Abuf_x[(size_t)(m0 + r) * KTOT + j] = (__bf16)v;
    }
}

// ---------------------------------------------------------------------------
extern "C" void kernel_launch(void* const* d_in, const int* in_sizes, int n_in,
                              void* d_out, int out_size, void* d_ws, size_t ws_size,
                              hipStream_t stream) {
    (void)in_sizes; (void)n_in; (void)out_size; (void)ws_size;
    const float* x      = (const float*)d_in[0];
    const float* kern   = (const float*)d_in[1];
    const float* rec    = (const float*)d_in[2];
    const float* bias   = (const float*)d_in[3];
    const float* period = (const float*)d_in[4];
    const float* phase  = (const float*)d_in[5];
    const float* ratio  = (const float*)d_in[6];
    const float* w1 = (const float*)d_in[7];
    const float* b1 = (const float*)d_in[8];
    const float* w2 = (const float*)d_in[9];
    const float* b2 = (const float*)d_in[10];
    const float* w3 = (const float*)d_in[11];
    const float* b3 = (const float*)d_in[12];
    const float* wo = (const float*)d_in[13];
    const float* bo = (const float*)d_in[14];
    float* out = (float*)d_out;

    char* ws = (char*)d_ws;
    const size_t WCAT_B = (size_t)NROWS * KTOT * 2;        // 8,912,896
    const size_t AB_B   = (size_t)BATCH * KTOT * 2;        // 557,056
    const size_t HC_B   = (size_t)BATCH * UNITS * 4;       // 1,048,576
    __bf16* Wcat = (__bf16*)ws;
    __bf16* Ab0  = (__bf16*)(ws + WCAT_B);
    __bf16* Ab1  = (__bf16*)(ws + WCAT_B + AB_B);
    float*  hT   = (float*)(ws + WCAT_B + 2 * AB_B);
    float*  cT   = hT + (size_t)BATCH * UNITS;
    float*  a1   = (float*)(ws + WCAT_B + 2 * AB_B + 2 * HC_B);
    float*  tvx  = a1 + (size_t)BATCH * 256;
    unsigned char* kflag = (unsigned char*)(tvx + (size_t)TSTEPS * BATCH);
    unsigned int*  ctr   = (unsigned int*)(kflag + (size_t)TSTEPS * BATCH);

    (void)hipFuncSetAttribute((const void*)rnn_steps,
                              hipFuncAttributeMaxDynamicSharedMemorySize,
                              (int)SMEM_BYTES);

    prep_weights<<<dim3(64, 17), 256, 0, stream>>>(kern, rec, Wcat);
    prep_state<<<512, 256, 0, stream>>>(x, Ab0, Ab1, hT, ctr);
    prep_tv<<<256, 256, 0, stream>>>(x, tvx, kflag);

    // warm phase: one persistent launch, 512 steps internally
    rnn_steps<<<dim3(256), dim3(256), SMEM_BYTES, stream>>>(
        Wcat, Ab0, Ab1, hT, cT, bias, period, phase, ratio,
        tvx, kflag, nullptr, 0, x, ctr, TSTEPS, 0);

    int rp = 0;  // read parity after 512 steps
    for (int s = 0; s < OUTSTEPS; s++) {
        dense1T<<<64, 256, 0, stream>>>(hT, w1, b1, a1);
        dense_tail<<<32, 256, 0, stream>>>(a1, w2, b2, w3, b3, wo, bo, out,
                                           rp ? Ab1 : Ab0, s);
        if (s < OUTSTEPS - 1) {
            rnn_steps<<<dim3(256), dim3(256), SMEM_BYTES, stream>>>(
                Wcat, Ab0, Ab1, hT, cT, bias, period, phase, ratio,
                nullptr, nullptr, out + (size_t)s * FEAT, OUTSTEPS * FEAT,
                nullptr, ctr, 1, rp);
            rp ^= 1;
        }
    }
}

// Round 2
// 7140.427 us; speedup vs baseline: 2.0554x; 1.8616x over previous
//
#include <hip/hip_runtime.h>
#include <hip/hip_bf16.h>

#define UNITS 1024
#define FEAT  16
#define TSTEPS 512
#define OUTSTEPS 24
#define BATCH 256
#define KTOT  1088   // 16 (x) + 1024 (h) + 48 pad
#define KP    1096   // padded LDS stride (2192B = 137*16B), conflict-reduced b128
#define NROWS 4096   // 4*UNITS, reordered r = 4*u + gate

// LDS: Ws [64][KP] bf16 (140288) + red [256][4] f32x4 (16384) + hstage [64][16] bf16 (2048)
#define RED_OFF   (64 * KP * 2)
#define HST_OFF   (RED_OFF + 16384)
#define SMEM_BYTES (HST_OFF + 2048)   // 158,720 <= 160 KiB

typedef __bf16 bf16x8 __attribute__((ext_vector_type(8)));
typedef float  f32x4  __attribute__((ext_vector_type(4)));

__device__ __forceinline__ float sigmoidf_(float x) { return 1.f / (1.f + __expf(-x)); }
__device__ __forceinline__ float tanhf_(float x)    { return 1.f - 2.f / (__expf(2.f * x) + 1.f); }

// ---------------------------------------------------------------------------
// Build Wcat_T[r][k] (bf16, row-major, stride KTOT), r = 4*u + g -> orig col
// ---------------------------------------------------------------------------
__global__ __launch_bounds__(256) void prep_weights(const float* __restrict__ kern,
                                                    const float* __restrict__ rec,
                                                    __bf16* __restrict__ Wcat) {
    __shared__ __align__(16) __bf16 tile[64][72];
    int r0 = blockIdx.x * 64;
    int k0 = blockIdx.y * 64;
    int t  = threadIdx.x;
    int c_off = t & 63;
    int k_grp = t >> 6;
    int g = c_off >> 4, ui = c_off & 15;
    int u0 = r0 >> 2;
    int c  = g * 1024 + u0 + ui;
    int rl = 4 * ui + g;
    for (int i = 0; i < 16; i++) {
        int k = k0 + k_grp * 16 + i;
        float v = 0.f;
        if (k < 16)        v = kern[(size_t)k * NROWS + c];
        else if (k < 1040) v = rec[(size_t)(k - 16) * NROWS + c];
        tile[rl][k_grp * 16 + i] = (__bf16)v;
    }
    __syncthreads();
    int rl2 = t >> 2, ch = t & 3;
    bf16x8* dst = (bf16x8*)(Wcat + (size_t)(r0 + rl2) * KTOT + k0 + ch * 16);
    const bf16x8* src = (const bf16x8*)&tile[rl2][ch * 16];
    dst[0] = src[0];
    dst[1] = src[1];
}

// ---------------------------------------------------------------------------
// Zero hT/cT, zero+x-init Abuf buffers, zero barrier counters.
// ---------------------------------------------------------------------------
__global__ __launch_bounds__(256) void prep_state(const float* __restrict__ x,
                                                  __bf16* __restrict__ Ab0,
                                                  __bf16* __restrict__ Ab1,
                                                  float* __restrict__ hc,
                                                  unsigned int* __restrict__ ctr) {
    int tid = blockIdx.x * 256 + threadIdx.x;
    int np  = gridDim.x * 256;
    for (int i = tid; i < 2 * BATCH * UNITS; i += np) hc[i] = 0.f;
    const int AB = BATCH * KTOT;
    for (int i = tid; i < 2 * AB; i += np) {
        int which = (i < AB) ? 0 : 1;
        int p = i - which * AB;
        int col = p % KTOT;
        int m   = p / KTOT;
        __bf16 v = (__bf16)0.f;
        if (which == 0 && col < FEAT) v = (__bf16)x[(size_t)m * TSTEPS * FEAT + col];
        if (which == 0) Ab0[p] = v; else Ab1[p] = v;
    }
    for (int i = tid; i < 512 * 4 * 16; i += np) ctr[i] = 0u;
}

// ---------------------------------------------------------------------------
// Precompute per-(t,m): tv, keep-flag, and bf16 x table xbf[t][m][16].
// ---------------------------------------------------------------------------
__global__ __launch_bounds__(256) void prep_tv(const float* __restrict__ x,
                                               float* __restrict__ tvx,
                                               unsigned char* __restrict__ kflag,
                                               __bf16* __restrict__ xbf) {
    int m = blockIdx.x;
    for (int t = threadIdx.x; t < TSTEPS; t += 256) {
        const float* row = x + ((size_t)m * TSTEPS + t) * FEAT;
        f32x4 v0 = *(const f32x4*)row;
        f32x4 v1 = *(const f32x4*)(row + 4);
        f32x4 v2 = *(const f32x4*)(row + 8);
        f32x4 v3 = *(const f32x4*)(row + 12);
        bool keep = true;
#pragma unroll
        for (int i = 0; i < 4; ++i)
            keep = keep && (v0[i] == -1.f) && (v1[i] == -1.f) &&
                   (v2[i] == -1.f) && (v3[i] == -1.f);
        tvx[(size_t)t * BATCH + m]   = v0[0];
        kflag[(size_t)t * BATCH + m] = keep ? 1 : 0;
        __bf16* xo = xbf + ((size_t)t * BATCH + m) * 16;
        bf16x8 o0, o1;
#pragma unroll
        for (int i = 0; i < 4; ++i) { o0[i] = (__bf16)v0[i]; o0[4 + i] = (__bf16)v1[i]; }
#pragma unroll
        for (int i = 0; i < 4; ++i) { o1[i] = (__bf16)v2[i]; o1[4 + i] = (__bf16)v3[i]; }
        *(bf16x8*)xo = o0;
        *(bf16x8*)(xo + 8) = o1;
    }
}

// ---------------------------------------------------------------------------
// Gate + phased update for one (unit, batch) pair held entirely in one lane.
// ---------------------------------------------------------------------------
__device__ __forceinline__ void gate_update(
    float z0, float z1, float z2, float z3,
    float bi, float bf, float bg, float bo,
    float ph, float rp, float ro, float k2,
    float tv, int kf, float& h, float& c) {
    float zi = z0 + bi, zf = z1 + bf, zg = z2 + bg, zo = z3 + bo;
    float ig = sigmoidf_(zi), fg = sigmoidf_(zf), og = sigmoidf_(zo);
    float gv = tanhf_(zg);
    float nc = fg * c + ig * gv;
    float nh = og * tanhf_(nc);
    float cr = (tv - ph) * rp;
    cr = cr - floorf(cr);
    float kup = cr * k2;
    float kk = (cr < ro) ? (2.f - kup) : (0.001f * cr);
    kk = (cr < 0.5f * ro) ? kup : kk;
    float ho = kk * nh + (1.f - kk) * h;
    float co = kk * nc + (1.f - kk) * c;
    if (kf) { ho = h; co = c; }
    h = ho; c = co;
}

// ---------------------------------------------------------------------------
// Persistent multi-step PLSTM kernel. Grid 256 x 512 thr, 1 block/CU.
// Block (gb 0..3 batch-group, rb 0..63 weight-row-block):
//   Wcat rows [rb*64,+64) LDS-resident (A-op). Waves = (wm 0..3)x(kh 0..1):
//   wave owns 16 batch rows (B dedup) and K-half kh; K-halves reduced in LDS.
//   All cross-block comm: sc0/sc1 asm loads + agent-relaxed atomic stores.
//   NO fences -> no buffer_wbl2 / buffer_inv in the loop.
// ---------------------------------------------------------------------------
#define KSTEP(BF, KT) { \
    const __bf16* ap_ = wsbase + (KT) * 32; \
    bf16x8 a0_ = *(const bf16x8*)(ap_); \
    bf16x8 a1_ = *(const bf16x8*)(ap_ + 16 * KP); \
    bf16x8 a2_ = *(const bf16x8*)(ap_ + 32 * KP); \
    bf16x8 a3_ = *(const bf16x8*)(ap_ + 48 * KP); \
    acc0 = __builtin_amdgcn_mfma_f32_16x16x32_bf16(a0_, BF, acc0, 0, 0, 0); \
    acc1 = __builtin_amdgcn_mfma_f32_16x16x32_bf16(a1_, BF, acc1, 0, 0, 0); \
    acc2 = __builtin_amdgcn_mfma_f32_16x16x32_bf16(a2_, BF, acc2, 0, 0, 0); \
    acc3 = __builtin_amdgcn_mfma_f32_16x16x32_bf16(a3_, BF, acc3, 0, 0, 0); \
}

#define DECL_PARAMS(R, UU) \
    float Bi##R = bias[UU], Bf##R = bias[UNITS + UU], \
          Bg##R = bias[2 * UNITS + UU], Bo##R = bias[3 * UNITS + UU]; \
    float Ph##R = phase[UU], Rp##R = 1.f / period[UU]; \
    float Ro##R = ratio[UU], K2##R = 2.f / Ro##R; \
    float h##R = hT[(size_t)(UU) * BATCH + mm], c##R = cT[(size_t)(UU) * BATCH + mm];

#define GUPD(R, ACC) { \
    f32x4 rr_ = red[(wm * 64 + lane) * 4 + R]; \
    ACC += rr_; \
    gate_update(ACC[0], ACC[1], ACC[2], ACC[3], \
                Bi##R, Bf##R, Bg##R, Bo##R, Ph##R, Rp##R, Ro##R, K2##R, \
                tvf, kf, h##R, c##R); \
    hstage[(wm * 16 + l16) * 16 + R * 4 + quad] = (__bf16)h##R; \
}

__global__ __launch_bounds__(512, 2) void rnn_steps(
    const __bf16* __restrict__ Wcat,
    __bf16* __restrict__ Ab0, __bf16* __restrict__ Ab1,
    float* __restrict__ hT, float* __restrict__ cT,
    const float* __restrict__ bias, const float* __restrict__ period,
    const float* __restrict__ phase, const float* __restrict__ ratio,
    const float* __restrict__ tvx, const unsigned char* __restrict__ kflag,
    const float* __restrict__ tsrc, int tv_mstride,
    const __bf16* __restrict__ xbf,
    unsigned int* ctr, int nsteps, int par0) {
    extern __shared__ __align__(16) char smem[];
    __bf16* Ws     = (__bf16*)smem;                 // [64][KP]
    f32x4*  red    = (f32x4*)(smem + RED_OFF);      // [4*64][4]
    __bf16* hstage = (__bf16*)(smem + HST_OFF);     // [64][16]

    int b   = blockIdx.x;
    int gb  = b & 3, rb = b >> 2;
    int tid = threadIdx.x;
    int wave = tid >> 6, lane = tid & 63;
    int wm = wave & 3, kh = wave >> 2;
    int l16 = lane & 15, quad = lane >> 4;
    int gm0 = gb * 64, r0 = rb * 64, u0 = rb * 16;

    // one-time: stage Wcat slice into LDS
    for (int i = tid; i < 64 * 136; i += 512) {
        int rr = i / 136, cc = i - rr * 136;
        *(bf16x8*)&Ws[rr * KP + cc * 8] =
            *(const bf16x8*)&Wcat[(size_t)(r0 + rr) * KTOT + cc * 8];
    }

    int mm = gm0 + wm * 16 + l16;           // this lane's batch row
    int uu0 = u0 + quad, uu1 = u0 + 4 + quad, uu2 = u0 + 8 + quad, uu3 = u0 + 12 + quad;
    DECL_PARAMS(0, uu0)
    DECL_PARAMS(1, uu1)
    DECL_PARAMS(2, uu2)
    DECL_PARAMS(3, uu3)

    const __bf16* wsbase = Ws + (size_t)l16 * KP + quad * 8 + kh * 544;
    const __bf16* ba0 = Ab0 + (size_t)mm * KTOT + quad * 8 + kh * 544;
    const __bf16* ba1 = Ab1 + (size_t)mm * KTOT + quad * 8 + kh * 544;
    const bool warm = (tvx != nullptr);

    __syncthreads();   // Ws ready

#pragma unroll 1
    for (int t = 0; t < nsteps; ++t) {
        int par = (par0 + t) & 1;
        const __bf16* bp = par ? ba1 : ba0;
        __bf16*       Aw = par ? Ab0 : Ab1;
        const float* tva = warm ? (tvx + (size_t)t * BATCH + mm)
                                : (tsrc + (size_t)mm * tv_mstride);
        const unsigned char* kfa = warm ? (kflag + (size_t)t * BATCH + mm)
                                        : (const unsigned char*)tva;

        bf16x8 b0, b1, b2, b3, b4, b5, b6, b7, b8, b9, b10, b11, b12, b13, b14, b15, b16;
        float tvr;
        unsigned int kfr;
        // 19 in-order loads: b0..b16 (this wave's K-half of its 16 batch rows),
        // tv, kflag. sc0 sc1 => bypass (possibly stale) L1/L2; data comes from
        // the coherence point, so no acquire fence is needed.
        asm volatile(
            "global_load_dwordx4 %0, %19, off sc0 sc1\n\t"
            "global_load_dwordx4 %1, %19, off offset:64 sc0 sc1\n\t"
            "global_load_dwordx4 %2, %19, off offset:128 sc0 sc1\n\t"
            "global_load_dwordx4 %3, %19, off offset:192 sc0 sc1\n\t"
            "global_load_dwordx4 %4, %19, off offset:256 sc0 sc1\n\t"
            "global_load_dwordx4 %5, %19, off offset:320 sc0 sc1\n\t"
            "global_load_dwordx4 %6, %19, off offset:384 sc0 sc1\n\t"
            "global_load_dwordx4 %7, %19, off offset:448 sc0 sc1\n\t"
            "global_load_dwordx4 %8, %19, off offset:512 sc0 sc1\n\t"
            "global_load_dwordx4 %9, %19, off offset:576 sc0 sc1\n\t"
            "global_load_dwordx4 %10, %19, off offset:640 sc0 sc1\n\t"
            "global_load_dwordx4 %11, %19, off offset:704 sc0 sc1\n\t"
            "global_load_dwordx4 %12, %19, off offset:768 sc0 sc1\n\t"
            "global_load_dwordx4 %13, %19, off offset:832 sc0 sc1\n\t"
            "global_load_dwordx4 %14, %19, off offset:896 sc0 sc1\n\t"
            "global_load_dwordx4 %15, %19, off offset:960 sc0 sc1\n\t"
            "global_load_dwordx4 %16, %19, off offset:1024 sc0 sc1\n\t"
            "global_load_dword %17, %20, off sc0 sc1\n\t"
            "global_load_ubyte %18, %21, off sc0 sc1"
            : "=&v"(b0), "=&v"(b1), "=&v"(b2), "=&v"(b3), "=&v"(b4), "=&v"(b5),
              "=&v"(b6), "=&v"(b7), "=&v"(b8), "=&v"(b9), "=&v"(b10), "=&v"(b11),
              "=&v"(b12), "=&v"(b13), "=&v"(b14), "=&v"(b15), "=&v"(b16),
              "=&v"(tvr), "=&v"(kfr)
            : "v"(bp), "v"(tva), "v"(kfa)
            : "memory");

        f32x4 acc0 = {}, acc1 = {}, acc2 = {}, acc3 = {};

        asm volatile("s_waitcnt vmcnt(8)" ::: "memory");   // b0..b10 landed
        __builtin_amdgcn_sched_barrier(0);
        KSTEP(b0, 0)  KSTEP(b1, 1)  KSTEP(b2, 2)  KSTEP(b3, 3)  KSTEP(b4, 4)
        KSTEP(b5, 5)  KSTEP(b6, 6)  KSTEP(b7, 7)  KSTEP(b8, 8)
        asm volatile("s_waitcnt vmcnt(0)" ::: "memory");   // all landed
        __builtin_amdgcn_sched_barrier(0);
        KSTEP(b9, 9)  KSTEP(b10, 10) KSTEP(b11, 11) KSTEP(b12, 12)
        KSTEP(b13, 13) KSTEP(b14, 14) KSTEP(b15, 15) KSTEP(b16, 16)

        if (kh) {   // K-half 1: park partials in LDS
            red[(wm * 64 + lane) * 4 + 0] = acc0;
            red[(wm * 64 + lane) * 4 + 1] = acc1;
            red[(wm * 64 + lane) * 4 + 2] = acc2;
            red[(wm * 64 + lane) * 4 + 3] = acc3;
        }
        __syncthreads();
        if (!kh) {  // K-half 0: reduce, gates, phased update, stage h
            float tvf = tvr;
            int kf = warm ? (int)kfr : 0;
            GUPD(0, acc0)
            GUPD(1, acc1)
            GUPD(2, acc2)
            GUPD(3, acc3)
        }
        __syncthreads();
        if (tid < 256) {   // coalesced h copy-out (agent-scope, write-through)
            int ml = tid >> 2, c4 = tid & 3;
            unsigned long long v = *(const unsigned long long*)&hstage[ml * 16 + c4 * 4];
            __hip_atomic_store(
                (unsigned long long*)&Aw[(size_t)(gm0 + ml) * KTOT + 16 + u0 + c4 * 4],
                v, __ATOMIC_RELAXED, __HIP_MEMORY_SCOPE_AGENT);
        } else if (warm && t + 1 < nsteps) {   // stage next x (waves 4..7)
            int i = tid - 256, row = i >> 2, q = i & 3;
            unsigned long long v = *(const unsigned long long*)
                &xbf[((size_t)(t + 1) * BATCH + gm0 + row) * 16 + q * 4];
            __hip_atomic_store(
                (unsigned long long*)&Aw[(size_t)(gm0 + row) * KTOT + q * 4],
                v, __ATOMIC_RELAXED, __HIP_MEMORY_SCOPE_AGENT);
        }

        if (t + 1 < nsteps) {
            __syncthreads();   // drains vmcnt (compiler emits waitcnt before s_barrier)
            if (tid == 0) {
                unsigned int* cp_ = ctr + ((size_t)t * 4 + gb) * 16;
                __hip_atomic_fetch_add(cp_, 1u, __ATOMIC_RELAXED, __HIP_MEMORY_SCOPE_AGENT);
                while (__hip_atomic_load(cp_, __ATOMIC_RELAXED, __HIP_MEMORY_SCOPE_AGENT) < 64u)
                    __builtin_amdgcn_s_sleep(2);
            }
            __syncthreads();
        }
    }

    if (!kh) {   // dump register state (transposed [u][m])
        hT[(size_t)uu0 * BATCH + mm] = h0; cT[(size_t)uu0 * BATCH + mm] = c0;
        hT[(size_t)uu1 * BATCH + mm] = h1; cT[(size_t)uu1 * BATCH + mm] = c1;
        hT[(size_t)uu2 * BATCH + mm] = h2; cT[(size_t)uu2 * BATCH + mm] = c2;
        hT[(size_t)uu3 * BATCH + mm] = h3; cT[(size_t)uu3 * BATCH + mm] = c3;
    }
}

// ---------------------------------------------------------------------------
// Dense layer 1: a1 = tanh(hT^T @ w1 + b1), hT is [UNITS][BATCH].
// ---------------------------------------------------------------------------
__global__ __launch_bounds__(256) void dense1T(const float* __restrict__ hT,
                                               const float* __restrict__ w1,
                                               const float* __restrict__ b1,
                                               float* __restrict__ a1) {
    int m0 = blockIdx.x * 4;
    int j = threadIdx.x;
    float s0 = 0.f, s1 = 0.f, s2 = 0.f, s3 = 0.f;
    for (int k = 0; k < UNITS; k++) {
        float w = w1[(size_t)k * 256 + j];
        const float* hrow = hT + (size_t)k * BATCH + m0;
        s0 += hrow[0] * w;
        s1 += hrow[1] * w;
        s2 += hrow[2] * w;
        s3 += hrow[3] * w;
    }
    float bb = b1[j];
    a1[(size_t)(m0 + 0) * 256 + j] = tanhf_(s0 + bb);
    a1[(size_t)(m0 + 1) * 256 + j] = tanhf_(s1 + bb);
    a1[(size_t)(m0 + 2) * 256 + j] = tanhf_(s2 + bb);
    a1[(size_t)(m0 + 3) * 256 + j] = tanhf_(s3 + bb);
}

// ---------------------------------------------------------------------------
// Dense tail: L2,L3,L4 fused. Writes pred and (bf16) Abuf x-cols.
// ---------------------------------------------------------------------------
__global__ __launch_bounds__(256) void dense_tail(
    const float* __restrict__ a1, const float* __restrict__ w2, const float* __restrict__ b2,
    const float* __restrict__ w3, const float* __restrict__ b3, const float* __restrict__ wo,
    const float* __restrict__ bo, float* __restrict__ out, __bf16* __restrict__ Abuf_x, int s) {
    __shared__ float a1s[8][256];
    __shared__ float a2s[8][128];
    __shared__ float a3s[8][64];
    int m0 = blockIdx.x * 8;
    int t = threadIdx.x;
    for (int i = 0; i < 8; i++) {
        int idx = t + i * 256;
        int r = idx >> 8, c = idx & 255;
        a1s[r][c] = a1[(size_t)(m0 + r) * 256 + c];
    }
    __syncthreads();
    {
        int j = t & 127, rb = t >> 7;
        float acc[4] = {0.f, 0.f, 0.f, 0.f};
        for (int k = 0; k < 256; k++) {
            float w = w2[(size_t)k * 128 + j];
#pragma unroll
            for (int q = 0; q < 4; q++) acc[q] += a1s[rb * 4 + q][k] * w;
        }
        float bb = b2[j];
#pragma unroll
        for (int q = 0; q < 4; q++) a2s[rb * 4 + q][j] = tanhf_(acc[q] + bb);
    }
    __syncthreads();
    {
        int j = t & 63, rb = t >> 6;
        float acc[2] = {0.f, 0.f};
        for (int k = 0; k < 128; k++) {
            float w = w3[(size_t)k * 64 + j];
#pragma unroll
            for (int q = 0; q < 2; q++) acc[q] += a2s[rb * 2 + q][k] * w;
        }
        float bb = b3[j];
#pragma unroll
        for (int q = 0; q < 2; q++) a3s[rb * 2 + q][j] = tanhf_(acc[q] + bb);
    }
    __syncthreads();
    if (t < 128) {
        int j = t & 15, r = t >> 4;
        float acc = 0.f;
        for (int k = 0; k < 64; k++) acc += a3s[r][k] * wo[(size_t)k * 16 + j];
        float v = acc + bo[j];
        out[(size_t)(m0 + r) * (OUTSTEPS * FEAT) + s * FEAT + j] = v;
        Abuf_x[(size_t)(m0 + r) * KTOT + j] = (__bf16)v;
    }
}

// ---------------------------------------------------------------------------
extern "C" void kernel_launch(void* const* d_in, const int* in_sizes, int n_in,
                              void* d_out, int out_size, void* d_ws, size_t ws_size,
                              hipStream_t stream) {
    (void)in_sizes; (void)n_in; (void)out_size; (void)ws_size;
    const float* x      = (const float*)d_in[0];
    const float* kern   = (const float*)d_in[1];
    const float* rec    = (const float*)d_in[2];
    const float* bias   = (const float*)d_in[3];
    const float* period = (const float*)d_in[4];
    const float* phase  = (const float*)d_in[5];
    const float* ratio  = (const float*)d_in[6];
    const float* w1 = (const float*)d_in[7];
    const float* b1 = (const float*)d_in[8];
    const float* w2 = (const float*)d_in[9];
    const float* b2 = (const float*)d_in[10];
    const float* w3 = (const float*)d_in[11];
    const float* b3 = (const float*)d_in[12];
    const float* wo = (const float*)d_in[13];
    const float* bo = (const float*)d_in[14];
    float* out = (float*)d_out;

    char* ws = (char*)d_ws;
    const size_t WCAT_B = (size_t)NROWS * KTOT * 2;        // 8,912,896
    const size_t AB_B   = (size_t)BATCH * KTOT * 2;        // 557,056
    const size_t HC_B   = (size_t)BATCH * UNITS * 4;       // 1,048,576
    __bf16* Wcat = (__bf16*)ws;
    __bf16* Ab0  = (__bf16*)(ws + WCAT_B);
    __bf16* Ab1  = (__bf16*)(ws + WCAT_B + AB_B);
    float*  hT   = (float*)(ws + WCAT_B + 2 * AB_B);
    float*  cT   = hT + (size_t)BATCH * UNITS;
    float*  a1   = (float*)(ws + WCAT_B + 2 * AB_B + 2 * HC_B);
    float*  tvx  = a1 + (size_t)BATCH * 256;
    __bf16* xbf  = (__bf16*)(tvx + (size_t)TSTEPS * BATCH);
    unsigned char* kflag = (unsigned char*)(xbf + (size_t)TSTEPS * BATCH * 16);
    unsigned int*  ctr   = (unsigned int*)(kflag + (size_t)TSTEPS * BATCH);

    (void)hipFuncSetAttribute((const void*)rnn_steps,
                              hipFuncAttributeMaxDynamicSharedMemorySize,
                              (int)SMEM_BYTES);

    prep_weights<<<dim3(64, 17), 256, 0, stream>>>(kern, rec, Wcat);
    prep_state<<<512, 256, 0, stream>>>(x, Ab0, Ab1, hT, ctr);
    prep_tv<<<256, 256, 0, stream>>>(x, tvx, kflag, xbf);

    // warm phase: one persistent launch, 512 steps internally
    rnn_steps<<<dim3(256), dim3(512), SMEM_BYTES, stream>>>(
        Wcat, Ab0, Ab1, hT, cT, bias, period, phase, ratio,
        tvx, kflag, nullptr, 0, xbf, ctr, TSTEPS, 0);

    int rp = 0;  // parity the next step READS (512 even -> 0)
    for (int s = 0; s < OUTSTEPS; s++) {
        dense1T<<<64, 256, 0, stream>>>(hT, w1, b1, a1);
        dense_tail<<<32, 256, 0, stream>>>(a1, w2, b2, w3, b3, wo, bo, out,
                                           rp ? Ab1 : Ab0, s);
        if (s < OUTSTEPS - 1) {
            rnn_steps<<<dim3(256), dim3(512), SMEM_BYTES, stream>>>(
                Wcat, Ab0, Ab1, hT, cT, bias, period, phase, ratio,
                nullptr, nullptr, out + (size_t)s * FEAT, OUTSTEPS * FEAT,
                nullptr, ctr, 1, rp);
            rp ^= 1;
        }
    }
}